// Round 1
// baseline (3150.018 us; speedup 1.0000x reference)
//
#include <hip/hip_runtime.h>
#include <cstddef>

#define T_LEN 512
#define IN_D 8
#define H 32
#define KDIM 40          // 32 h + 8 x
#define BPW 32           // batches per workgroup
#define JT 4             // hidden units per thread
#define NT 256

__device__ __forceinline__ float fast_exp2(float v) {
#if __has_builtin(__builtin_amdgcn_exp2f)
    return __builtin_amdgcn_exp2f(v);
#else
    return exp2f(v);
#endif
}
__device__ __forceinline__ float fast_rcp(float v) {
#if __has_builtin(__builtin_amdgcn_rcpf)
    return __builtin_amdgcn_rcpf(v);
#else
    return 1.0f / v;
#endif
}
__device__ __forceinline__ float sigm(float v) {
    // 1/(1+exp(-v)) via exp2
    return fast_rcp(1.0f + fast_exp2(v * -1.44269504088896341f));
}
__device__ __forceinline__ float tanh_fast(float v) {
    // tanh(v) = 1 - 2/(1+exp(2v)); exp2 overflow -> inf -> rcp=0 -> 1  (correct limit)
    return 1.0f - 2.0f * fast_rcp(1.0f + fast_exp2(v * 2.88539008177792681f));
}

// Thread mapping: tid = p*32 + b.  b = batch-within-WG (0..31), p = j-part (0..7),
// thread owns hidden units j0..j0+3 (j0 = 4p), all 4 gates (i,f,g,o).
// LDS:
//  Wp[k][r]: r = gate*32 + j (row of the 4H x (H+D) concat weight), k in [0,40):
//            k<32 -> W_hh[r][k], k>=32 -> W_ih[r][k-32].  Read as same-address
//            float4 broadcasts per half-wave (cheap).
//  st[k][b]: k<32 -> h[k] of batch b; k>=32 -> x_t[k-32] of batch b.
//            Row stride 33 -> bank (k+b)%32, conflict-free for lanes b=0..31.
__global__ void __launch_bounds__(NT) lstm_fused(
    const float* __restrict__ x, const float* __restrict__ W_ih,
    const float* __restrict__ W_hh, const float* __restrict__ b_ih,
    const float* __restrict__ b_hh, const float* __restrict__ W_fc,
    const float* __restrict__ b_fc, float* __restrict__ out)
{
    __shared__ __align__(16) float Wp[KDIM][128];
    __shared__ float st[KDIM][BPW + 1];
    __shared__ float wfc[H];

    const int tid = threadIdx.x;
    const int b   = tid & (BPW - 1);
    const int p   = tid >> 5;
    const int j0  = p * JT;

    // ---- stage weights into LDS (once) ----
    for (int i = tid; i < KDIM * 128; i += NT) {
        int k = i >> 7, r = i & 127;
        Wp[k][r] = (k < H) ? W_hh[r * H + k] : W_ih[r * IN_D + (k - H)];
    }
    if (tid < H) wfc[tid] = W_fc[tid];
    for (int k = p; k < H; k += NT / BPW) st[k][b] = 0.0f;   // h0 = 0

    // combined bias per owned row, kept in registers
    float bias[JT][4];
    #pragma unroll
    for (int jt = 0; jt < JT; ++jt) {
        #pragma unroll
        for (int g = 0; g < 4; ++g) {
            int r = g * H + j0 + jt;
            bias[jt][g] = b_ih[r] + b_hh[r];
        }
    }

    // x staging mapping: thread (xb, xd) loads x[wg*32+xb][t][xd] (32B/batch, coalesced-ish)
    const int xb = tid >> 3, xd = tid & 7;
    const float* xp = x + (size_t)(blockIdx.x * BPW + xb) * (size_t)(T_LEN * IN_D) + xd;
    st[H + xd][xb] = xp[0];          // x[0] into state
    __syncthreads();

    float c[JT];
    #pragma unroll
    for (int jt = 0; jt < JT; ++jt) c[jt] = 0.0f;

    for (int t = 0; t < T_LEN; ++t) {
        // prefetch next x early; latency hides behind the k-loop
        int tn = (t + 1 < T_LEN) ? t + 1 : t;
        float xr = xp[(size_t)tn * IN_D];

        float acc[JT][4];
        #pragma unroll
        for (int jt = 0; jt < JT; ++jt)
            #pragma unroll
            for (int g = 0; g < 4; ++g) acc[jt][g] = bias[jt][g];

        #pragma unroll
        for (int k = 0; k < KDIM; ++k) {
            float s = st[k][b];
            #pragma unroll
            for (int g = 0; g < 4; ++g) {
                const float4 w = *(const float4*)(&Wp[k][g * H + j0]);
                acc[0][g] += w.x * s;
                acc[1][g] += w.y * s;
                acc[2][g] += w.z * s;
                acc[3][g] += w.w * s;
            }
        }

        float hn[JT];
        #pragma unroll
        for (int jt = 0; jt < JT; ++jt) {
            float ig = sigm(acc[jt][0]);
            float fg = sigm(acc[jt][1]);
            float gg = tanh_fast(acc[jt][2]);
            float og = sigm(acc[jt][3]);
            c[jt] = fg * c[jt] + ig * gg;
            hn[jt] = og * tanh_fast(c[jt]);
        }

        __syncthreads();                       // all state reads done
        #pragma unroll
        for (int jt = 0; jt < JT; ++jt) st[j0 + jt][b] = hn[jt];
        st[H + xd][xb] = xr;                   // x[t+1]
        __syncthreads();                       // writes visible
    }

    // epilogue: out[b] = h_n . W_fc + b_fc
    if (tid < BPW) {
        float s = b_fc[0];
        #pragma unroll
        for (int j = 0; j < H; ++j) s += st[j][tid] * wfc[j];
        out[blockIdx.x * BPW + tid] = s;
    }
}

extern "C" void kernel_launch(void* const* d_in, const int* in_sizes, int n_in,
                              void* d_out, int out_size, void* d_ws, size_t ws_size,
                              hipStream_t stream) {
    const float* x    = (const float*)d_in[0];
    const float* W_ih = (const float*)d_in[1];
    const float* W_hh = (const float*)d_in[2];
    const float* b_ih = (const float*)d_in[3];
    const float* b_hh = (const float*)d_in[4];
    const float* W_fc = (const float*)d_in[5];
    const float* b_fc = (const float*)d_in[6];
    float* out = (float*)d_out;
    const int Bn = in_sizes[0] / (T_LEN * IN_D);   // 8192
    lstm_fused<<<dim3(Bn / BPW), dim3(NT), 0, stream>>>(
        x, W_ih, W_hh, b_ih, b_hh, W_fc, b_fc, out);
}

// Round 2
// 2018.716 us; speedup vs baseline: 1.5604x; 1.5604x over previous
//
#include <hip/hip_runtime.h>
#include <cstddef>

#define T_LEN 512
#define IN_D 8
#define H 32
#define KDIM 40          // 32 h + 8 x
#define KP 44            // padded k stride (bank rotate 12, 16B-aligned)
#define BPW 16           // batches per workgroup
#define NB 4             // batches per thread
#define NT 128           // 32 j-threads x 4 batch-groups = 2 waves

__device__ __forceinline__ float fast_exp2(float v) {
#if __has_builtin(__builtin_amdgcn_exp2f)
    return __builtin_amdgcn_exp2f(v);
#else
    return exp2f(v);
#endif
}
__device__ __forceinline__ float fast_rcp(float v) {
#if __has_builtin(__builtin_amdgcn_rcpf)
    return __builtin_amdgcn_rcpf(v);
#else
    return 1.0f / v;
#endif
}
__device__ __forceinline__ float sigm(float v) {
    return fast_rcp(1.0f + fast_exp2(v * -1.44269504088896341f));
}
__device__ __forceinline__ float tanh_fast(float v) {
    // tanh(v) = 1 - 2/(1+exp(2v)); exp2 overflow -> inf -> rcp -> 0 -> 1 (correct limit)
    return 1.0f - 2.0f * fast_rcp(1.0f + fast_exp2(v * 2.88539008177792681f));
}

// Thread mapping: tid = bg*32 + j.  j = hidden unit (0..31), bg = batch-group (0..3).
// Thread owns: all 4 gates of unit j, for batches bg*4 .. bg*4+3.
// Wave = {bg, bg+1} x all 32 j  ->  W reads: 32 distinct b128 (dense, full BW);
//                                   state reads: 2-address broadcast b128 (cheap).
// LDS:
//  Wt[k][j*4+g]  : gates contiguous -> one b128 gives the 4 gate-weights of (k, j).
//  st[buf][b][k] : k<32 = h[k], k in [32,40) = x_t[k-32]; per-batch contiguous so
//                  4 consecutive k = one b128. Double-buffered -> 1 barrier/step.
__global__ void __launch_bounds__(NT) lstm_fused(
    const float* __restrict__ x, const float* __restrict__ W_ih,
    const float* __restrict__ W_hh, const float* __restrict__ b_ih,
    const float* __restrict__ b_hh, const float* __restrict__ W_fc,
    const float* __restrict__ b_fc, float* __restrict__ out)
{
    __shared__ __align__(16) float Wt[KDIM][128];
    __shared__ __align__(16) float st[2][BPW][KP];
    __shared__ float wfc[H];

    const int tid = threadIdx.x;
    const int j   = tid & 31;
    const int bg  = tid >> 5;          // 0..3
    const int b0  = bg * NB;

    // ---- stage weights: Wt[k][j*4+g] = Wcat[g*32+j][k] ----
    for (int i = tid; i < KDIM * 128; i += NT) {
        int k = i >> 7, r = i & 127;
        int jj = r >> 2, g = r & 3;
        int row = g * H + jj;
        Wt[k][r] = (k < H) ? W_hh[row * H + k] : W_ih[row * IN_D + (k - H)];
    }
    if (tid < H) wfc[tid] = W_fc[tid];
    // zero h0
    for (int i = tid; i < BPW * H; i += NT) st[0][i >> 5][i & 31] = 0.0f;

    // combined bias per gate (j fixed per thread)
    float bias[4];
    #pragma unroll
    for (int g = 0; g < 4; ++g) {
        int r = g * H + j;
        bias[g] = b_ih[r] + b_hh[r];
    }

    // x staging: thread (xb, xd) owns x[wg*BPW+xb][t][xd]
    const int xb = tid >> 3, xd = tid & 7;
    const float* xp = x + (size_t)(blockIdx.x * BPW + xb) * (size_t)(T_LEN * IN_D) + xd;
    st[0][xb][H + xd] = xp[0];
    __syncthreads();

    float c[NB];
    #pragma unroll
    for (int i = 0; i < NB; ++i) c[i] = 0.0f;

    float xnext = xp[IN_D];            // x[1]
    int cur = 0;

    for (int t = 0; t < T_LEN; ++t) {
        // depth-2 prefetch: load x[t+2] now, store x[t+1] (= xnext) at step end
        int t2 = (t + 2 < T_LEN) ? t + 2 : T_LEN - 1;
        float xfar = xp[(size_t)t2 * IN_D];

        float acc[NB][4];
        #pragma unroll
        for (int i = 0; i < NB; ++i)
            #pragma unroll
            for (int g = 0; g < 4; ++g) acc[i][g] = bias[g];

        #pragma unroll
        for (int kb = 0; kb < KDIM; kb += 4) {
            float4 wv[4];
            #pragma unroll
            for (int kk = 0; kk < 4; ++kk)
                wv[kk] = *(const float4*)(&Wt[kb + kk][j * 4]);   // gates 0..3 of (k, j)
            #pragma unroll
            for (int i = 0; i < NB; ++i) {
                const float4 sv = *(const float4*)(&st[cur][b0 + i][kb]); // s[kb..kb+3]
                acc[i][0] += wv[0].x * sv.x + wv[1].x * sv.y + wv[2].x * sv.z + wv[3].x * sv.w;
                acc[i][1] += wv[0].y * sv.x + wv[1].y * sv.y + wv[2].y * sv.z + wv[3].y * sv.w;
                acc[i][2] += wv[0].z * sv.x + wv[1].z * sv.y + wv[2].z * sv.z + wv[3].z * sv.w;
                acc[i][3] += wv[0].w * sv.x + wv[1].w * sv.y + wv[2].w * sv.z + wv[3].w * sv.w;
            }
        }

        const int nxt = cur ^ 1;
        #pragma unroll
        for (int i = 0; i < NB; ++i) {
            float ig = sigm(acc[i][0]);
            float fg = sigm(acc[i][1]);
            float gg = tanh_fast(acc[i][2]);
            float og = sigm(acc[i][3]);
            c[i] = fg * c[i] + ig * gg;
            st[nxt][b0 + i][j] = og * tanh_fast(c[i]);
        }
        st[nxt][xb][H + xd] = xnext;
        __syncthreads();
        xnext = xfar;
        cur = nxt;
    }

    // epilogue: out[b] = h_n . W_fc + b_fc
    if (tid < BPW) {
        float s = b_fc[0];
        #pragma unroll
        for (int jj = 0; jj < H; ++jj) s += st[cur][tid][jj] * wfc[jj];
        out[blockIdx.x * BPW + tid] = s;
    }
}

extern "C" void kernel_launch(void* const* d_in, const int* in_sizes, int n_in,
                              void* d_out, int out_size, void* d_ws, size_t ws_size,
                              hipStream_t stream) {
    const float* x    = (const float*)d_in[0];
    const float* W_ih = (const float*)d_in[1];
    const float* W_hh = (const float*)d_in[2];
    const float* b_ih = (const float*)d_in[3];
    const float* b_hh = (const float*)d_in[4];
    const float* W_fc = (const float*)d_in[5];
    const float* b_fc = (const float*)d_in[6];
    float* out = (float*)d_out;
    const int Bn = in_sizes[0] / (T_LEN * IN_D);   // 8192
    lstm_fused<<<dim3(Bn / BPW), dim3(NT), 0, stream>>>(
        x, W_ih, W_hh, b_ih, b_hh, W_fc, b_fc, out);
}

// Round 3
// 979.384 us; speedup vs baseline: 3.2163x; 2.0612x over previous
//
#include <hip/hip_runtime.h>
#include <cstddef>

#define T_LEN 512
#define IN_D 8
#define H 32
#define KDIM 40          // 32 h + 8 x
#define KP 44            // padded k stride: 44 floats = 176 B = 11x16 -> rows stay 16B-aligned
#define NBW 4            // batches per workgroup (= per wave)
#define NB 2             // batches per thread
#define NT 64            // one wave per WG: no inter-wave sync, barrier ~free

__device__ __forceinline__ float fast_exp2(float v) {
#if __has_builtin(__builtin_amdgcn_exp2f)
    return __builtin_amdgcn_exp2f(v);
#else
    return exp2f(v);
#endif
}
__device__ __forceinline__ float fast_rcp(float v) {
#if __has_builtin(__builtin_amdgcn_rcpf)
    return __builtin_amdgcn_rcpf(v);
#else
    return 1.0f / v;
#endif
}
__device__ __forceinline__ float sigm(float v) {
    return fast_rcp(1.0f + fast_exp2(v * -1.44269504088896341f));
}
__device__ __forceinline__ float tanh_fast(float v) {
    // tanh(v) = 1 - 2/(1+exp2(2v*log2e)); overflow -> inf -> rcp=0 -> 1 (correct limit)
    return 1.0f - 2.0f * fast_rcp(1.0f + fast_exp2(v * 2.88539008177792681f));
}

// Thread mapping: lane = bg*32 + j. j = hidden unit (0..31), bg = batch-group (0..1),
// thread owns all 4 gates of unit j for batches bg*2, bg*2+1.
// W is LOOP-INVARIANT -> held in 160 VGPRs per lane (wg[g][k]), loaded once,
// coalesced (row-contiguous per lane). Zero LDS traffic for W in the hot loop.
// State st[buf][b][k] (k<32: h, k>=32: x_t): reads are wave-broadcast (2 distinct
// addresses per instr = free), writes conflict-free. One barrier/step (dbuf).
struct StepIO {
    float (*cur)[KP];
    float (*nxt)[KP];
};

__device__ __forceinline__ void lstm_step(
    const float wg[4][KDIM], const float bias[4], float (&c)[NB],
    const float (*scur)[KP], float (*snxt)[KP],
    int j, int b0, int xb, int xd, float xnext)
{
    float acc[NB][4];
    #pragma unroll
    for (int i = 0; i < NB; ++i)
        #pragma unroll
        for (int g = 0; g < 4; ++g) acc[i][g] = bias[g];

    #pragma unroll
    for (int kb = 0; kb < KDIM; kb += 4) {
        #pragma unroll
        for (int i = 0; i < NB; ++i) {
            const float4 sv = *(const float4*)(&scur[b0 + i][kb]);  // broadcast read
            #pragma unroll
            for (int g = 0; g < 4; ++g)
                acc[i][g] += wg[g][kb] * sv.x + wg[g][kb + 1] * sv.y
                           + wg[g][kb + 2] * sv.z + wg[g][kb + 3] * sv.w;
        }
    }

    #pragma unroll
    for (int i = 0; i < NB; ++i) {
        float ig = sigm(acc[i][0]);
        float fg = sigm(acc[i][1]);
        float gg = tanh_fast(acc[i][2]);
        float og = sigm(acc[i][3]);
        c[i] = fg * c[i] + ig * gg;
        snxt[b0 + i][j] = og * tanh_fast(c[i]);
    }
    snxt[xb][H + xd] = xnext;
    __syncthreads();   // single-wave WG: compiles to waitcnt + cheap barrier
}

__global__ void __launch_bounds__(NT, 2) lstm_fused(
    const float* __restrict__ x, const float* __restrict__ W_ih,
    const float* __restrict__ W_hh, const float* __restrict__ b_ih,
    const float* __restrict__ b_hh, const float* __restrict__ W_fc,
    const float* __restrict__ b_fc, float* __restrict__ out)
{
    __shared__ __align__(16) float st[2][NBW][KP];

    const int tid = threadIdx.x;
    const int j   = tid & 31;
    const int bg  = tid >> 5;            // 0..1
    const int b0  = bg * NB;

    // ---- W into registers: wg[g][k] = Wcat[g*H+j][k], coalesced float4 loads ----
    float wg[4][KDIM];
    #pragma unroll
    for (int g = 0; g < 4; ++g) {
        const float* rowh = W_hh + (size_t)(g * H + j) * H;      // 128B per lane, lanes strided
        #pragma unroll
        for (int kq = 0; kq < H / 4; ++kq) {
            const float4 v = *(const float4*)(rowh + kq * 4);
            wg[g][kq * 4 + 0] = v.x; wg[g][kq * 4 + 1] = v.y;
            wg[g][kq * 4 + 2] = v.z; wg[g][kq * 4 + 3] = v.w;
        }
        const float* rowi = W_ih + (size_t)(g * H + j) * IN_D;   // 32B per lane
        #pragma unroll
        for (int kq = 0; kq < IN_D / 4; ++kq) {
            const float4 v = *(const float4*)(rowi + kq * 4);
            wg[g][H + kq * 4 + 0] = v.x; wg[g][H + kq * 4 + 1] = v.y;
            wg[g][H + kq * 4 + 2] = v.z; wg[g][H + kq * 4 + 3] = v.w;
        }
    }

    float bias[4];
    #pragma unroll
    for (int g = 0; g < 4; ++g) bias[g] = b_ih[g * H + j] + b_hh[g * H + j];

    // ---- x staging: lanes 0..31 cover (xb in 0..3) x (xd in 0..7); upper half mirrors ----
    const int xb = (tid & 31) >> 3, xd = tid & 7;
    const float* xp = x + (size_t)(blockIdx.x * NBW + xb) * (size_t)(T_LEN * IN_D) + xd;

    // init: h0 = 0, x[0] into state buffer 0
    for (int i = tid; i < NBW * H; i += NT) st[0][i >> 5][i & 31] = 0.0f;
    st[0][xb][H + xd] = xp[0];
    float c[NB];
    #pragma unroll
    for (int i = 0; i < NB; ++i) c[i] = 0.0f;
    float xnext = xp[IN_D];
    __syncthreads();

    for (int t = 0; t < T_LEN; t += 2) {
        // prefetch x[t+2], x[t+3] right after the barrier -> full step of latency cover
        const int ia = (t + 2 < T_LEN) ? t + 2 : T_LEN - 1;
        const int ib = (t + 3 < T_LEN) ? t + 3 : T_LEN - 1;
        const float xa = xp[(size_t)ia * IN_D];
        const float xc = xp[(size_t)ib * IN_D];

        lstm_step(wg, bias, c, st[0], st[1], j, b0, xb, xd, xnext);
        xnext = xa;
        lstm_step(wg, bias, c, st[1], st[0], j, b0, xb, xd, xnext);
        xnext = xc;
    }

    // epilogue: out[b] = h_n . W_fc + b_fc   (h_n is in st[0])
    if (tid < NBW) {
        float s = b_fc[0];
        #pragma unroll
        for (int jj = 0; jj < H; ++jj) s += st[0][tid][jj] * W_fc[jj];
        out[blockIdx.x * NBW + tid] = s;
    }
}

extern "C" void kernel_launch(void* const* d_in, const int* in_sizes, int n_in,
                              void* d_out, int out_size, void* d_ws, size_t ws_size,
                              hipStream_t stream) {
    const float* x    = (const float*)d_in[0];
    const float* W_ih = (const float*)d_in[1];
    const float* W_hh = (const float*)d_in[2];
    const float* b_ih = (const float*)d_in[3];
    const float* b_hh = (const float*)d_in[4];
    const float* W_fc = (const float*)d_in[5];
    const float* b_fc = (const float*)d_in[6];
    float* out = (float*)d_out;
    const int Bn = in_sizes[0] / (T_LEN * IN_D);   // 8192
    lstm_fused<<<dim3(Bn / NBW), dim3(NT), 0, stream>>>(
        x, W_ih, W_hh, b_ih, b_hh, W_fc, b_fc, out);
}